// Round 1
// 352.931 us; speedup vs baseline: 1.1733x; 1.1733x over previous
//
#include <hip/hip_runtime.h>
#include <stdint.h>

#define NEGF  (-1e30f)
#define LOG2E 1.4426950408889634f
#define LN2F  0.6931471805599453f

__device__ __forceinline__ float fexp2(float x) {
#if __has_builtin(__builtin_amdgcn_exp2f)
    return __builtin_amdgcn_exp2f(x);
#else
    return exp2f(x);
#endif
}
__device__ __forceinline__ float flog2(float x) {
#if __has_builtin(__builtin_amdgcn_logf)
    return __builtin_amdgcn_logf(x);
#else
    return log2f(x);
#endif
}
__device__ __forceinline__ float lse2(float a, float b) {
    float m  = fmaxf(a, b);
    float mn = fminf(a, b);
    return m + flog2(1.0f + fexp2(mn - m));
}
__device__ __forceinline__ float lse3(float a, float b, float c) {
    float m = fmaxf(fmaxf(a, b), c);
    float s = fexp2(a - m) + fexp2(b - m) + fexp2(c - m);
    return m + flog2(s);
}

// ---- LDS ring pipeline ------------------------------------------------------
// RB slots x 4KB (one full lp row, C=1024 f32) = 64 KB LDS.
// 4 global_load_lds issues per row (64 lanes x 16B = 1KB each).
// Counted wait: need row staged RB-2 iters ago -> allow newest 4*(RB-2)=56.
#define RB  16
#define VMW "s_waitcnt vmcnt(56)"

__device__ __forceinline__ void stage_row(const float* __restrict__ src, float* dst)
{
    const int lane = threadIdx.x;
    const float* g = src + (lane << 2);              // lane*16B within row
    __builtin_amdgcn_global_load_lds((const __attribute__((address_space(1))) void*)(g),
        (__attribute__((address_space(3))) void*)(dst), 16, 0, 0);
    __builtin_amdgcn_global_load_lds((const __attribute__((address_space(1))) void*)(g + 256),
        (__attribute__((address_space(3))) void*)(dst + 256), 16, 0, 0);
    __builtin_amdgcn_global_load_lds((const __attribute__((address_space(1))) void*)(g + 512),
        (__attribute__((address_space(3))) void*)(dst + 512), 16, 0, 0);
    __builtin_amdgcn_global_load_lds((const __attribute__((address_space(1))) void*)(g + 768),
        (__attribute__((address_space(3))) void*)(dst + 768), 16, 0, 0);
}

// Inline-asm LDS gathers: opaque to the compiler so it can never insert a
// pipeline-draining vmcnt(0) for LDS aliasing. m0=-1 re-established because the
// global_load_lds lowering clobbers m0 with the LDS base.
__device__ __forceinline__ void lds_read3(uint32_t sb, uint32_t o1, uint32_t o3,
                                          float& eb, float& e1, float& e3)
{
    asm volatile("s_mov_b32 m0, -1\n\t"
                 "ds_read_b32 %0, %3\n\t"
                 "ds_read_b32 %1, %4\n\t"
                 "ds_read_b32 %2, %5"
                 : "=&v"(eb), "=&v"(e1), "=&v"(e3)
                 : "v"(sb), "v"(sb + o1), "v"(sb + o3)
                 : "memory");
}
__device__ __forceinline__ void lds_read4(uint32_t sb, uint32_t o1, uint32_t o3, uint32_t o5,
                                          float& eb, float& e1, float& e3, float& e5)
{
    asm volatile("s_mov_b32 m0, -1\n\t"
                 "ds_read_b32 %0, %4\n\t"
                 "ds_read_b32 %1, %5\n\t"
                 "ds_read_b32 %2, %6\n\t"
                 "ds_read_b32 %3, %7"
                 : "=&v"(eb), "=&v"(e1), "=&v"(e3), "=&v"(e5)
                 : "v"(sb), "v"(sb + o1), "v"(sb + o3), "v"(sb + o5)
                 : "memory");
}

// One wave (64 lanes) per (utterance, direction). Lane i owns extended states
// 4i..4i+3 (S <= 201 <= 256). blockIdx.x <  N : forward alpha scan t=0..tm
//                             blockIdx.x >= N : backward beta  scan t=T-1..tm
__global__ __launch_bounds__(64, 1)
void ctc_scan(const float* __restrict__ lp, const int* __restrict__ tgt,
              const int* __restrict__ ilen, const int* __restrict__ tlen,
              float* __restrict__ wsA, float* __restrict__ wsB,
              int T, int N, int C, int L)
{
    __shared__ float ring[RB * 1024];                // 64 KB (C == 1024 fixed)

    const int  b      = blockIdx.x;
    const bool is_fwd = (b < N);
    const int  n      = is_fwd ? b : (b - N);
    const int  lane   = threadIdx.x;
    const int  len_t  = tlen[n];
    const int  len_in = ilen[n];
    const int  tm     = (len_in - 1) >> 1;
    const int  send   = 2 * len_t;                   // final blank state index

    const long tb = (long)n * L;
    auto getT = [&](int k) -> int {
        return (k >= 0 && k < len_t) ? tgt[tb + k] : 0;
    };
    const int lm1 = getT(2 * lane - 1);
    const int l1  = getT(2 * lane);                  // label of state 4i+1
    const int l2  = getT(2 * lane + 1);              // label of state 4i+3
    const int l3  = getT(2 * lane + 2);              // label of state 4i+5
    const uint32_t o1 = (uint32_t)l1 << 2;           // fixed per-lane LDS offsets
    const uint32_t o3 = (uint32_t)l2 << 2;
    const uint32_t o5 = (uint32_t)l3 << 2;
    const bool skip1 = (lane > 0) && (l1 != lm1);    // skip_ok[4i+1]
    const bool skip3 = (l2 != l1);                   // skip_ok[4i+3]
    const bool skip5 = (l3 != l2);                   // skip_ok[4i+5]
    const int  s0 = 4 * lane;
    const bool v0 = (s0     <= send);
    const bool v1 = (s0 + 1 <= send);
    const bool v2 = (s0 + 2 <= send);
    const bool v3 = (s0 + 3 <= send);

    const long   rstride = (long)N * C;              // floats per time row
    const float* row0    = lp + (long)n * C;
    const uint32_t ringb =
        (uint32_t)(uintptr_t)(const __attribute__((address_space(3))) void*)ring;

    if (is_fwd) {
        // ---- forward alpha: steps i=0..tm-1 consume rows 1..tm ----
        float eb0 = row0[0];
        float e10 = row0[l1];
        float a0 = (lane == 0) ? eb0 * LOG2E : NEGF;
        float a1 = (lane == 0 && 1 <= send) ? e10 * LOG2E : NEGF;
        float a2 = NEGF, a3 = NEGF;
        float p3 = __shfl_up(a3, 1, 64);             // loop-carried shfl(a3)

        const int nsteps = tm;
        const int lim    = len_in - 1;
        for (int j = 0; j < RB - 1; ++j) {           // prologue: rows 1..RB-1
            int r = 1 + j; if (r > lim) r = lim;
            stage_row(row0 + (long)r * rstride, ring + (j << 10));
        }
        asm volatile(VMW ::: "memory");              // row(step 0) landed
        float eb, e1, e3;
        lds_read3(ringb, o1, o3, eb, e1, e3);        // cur = step 0

        for (int i = 0; i < nsteps; ++i) {
            int r = i + RB; if (r > lim) r = lim;    // stage step i+RB-1
            stage_row(row0 + (long)r * rstride,
                      ring + (((i + RB - 1) & (RB - 1)) << 10));
            asm volatile("s_waitcnt lgkmcnt(0)" ::: "memory");
            __builtin_amdgcn_sched_barrier(0);       // rule #18 fence
            {   // fstep (log2 domain)
                float ebl = eb * LOG2E, e1l = e1 * LOG2E, e3l = e3 * LOG2E;
                float pm = (lane == 0) ? NEGF : p3;
                float n0 = lse2(a0, pm) + ebl;
                float n1 = lse3(a1, a0, skip1 ? pm : NEGF) + e1l;
                float n2 = lse2(a2, a1) + ebl;
                float n3 = lse3(a3, a2, skip3 ? a1 : NEGF) + e3l;
                a0 = v0 ? n0 : NEGF;
                a1 = v1 ? n1 : NEGF;
                a2 = v2 ? n2 : NEGF;
                a3 = v3 ? n3 : NEGF;
                p3 = __shfl_up(a3, 1, 64);           // for next iter; waits lazily
            }
            asm volatile(VMW ::: "memory");          // row(step i+1) landed
            uint32_t sb = ringb + (uint32_t)(((i + 1) & (RB - 1)) << 12);
            lds_read3(sb, o1, o3, eb, e1, e3);       // prefetch next step's values
        }
        asm volatile("s_waitcnt vmcnt(0) lgkmcnt(0)" ::: "memory");
        *((float4*)(wsA + (long)n * 256) + lane) = make_float4(a0, a1, a2, a3);
    } else {
        // ---- backward beta: steps i=0..nsteps-1 consume rows len_in-1..tm+1 ----
        float b0 = (s0     == send || s0     == send - 1) ? 0.0f : NEGF;
        float b1 = (s0 + 1 == send || s0 + 1 == send - 1) ? 0.0f : NEGF;
        float b2 = (s0 + 2 == send || s0 + 2 == send - 1) ? 0.0f : NEGF;
        float b3 = (s0 + 3 == send || s0 + 3 == send - 1) ? 0.0f : NEGF;
        b0 = v0 ? b0 : NEGF; b1 = v1 ? b1 : NEGF;
        b2 = v2 ? b2 : NEGF; b3 = v3 ? b3 : NEGF;
        // loop-carried shuffles of the STATE (eb is lane-uniform; lane+1's e1 is
        // our e5 read directly from LDS) -> shfl off the critical path
        float q0 = __shfl_down(b0, 1, 64);
        float q1 = __shfl_down(b1, 1, 64);

        const int nsteps = len_in - 1 - tm;
        for (int j = 0; j < RB - 1; ++j) {           // prologue: rows T-1 down
            int r = len_in - 1 - j; if (r < 0) r = 0;
            stage_row(row0 + (long)r * rstride, ring + (j << 10));
        }
        asm volatile(VMW ::: "memory");
        float eb, e1, e3, e5;
        lds_read4(ringb, o1, o3, o5, eb, e1, e3, e5);

        for (int i = 0; i < nsteps; ++i) {
            int r = len_in - 1 - (i + RB - 1); if (r < 0) r = 0;
            stage_row(row0 + (long)r * rstride,
                      ring + (((i + RB - 1) & (RB - 1)) << 10));
            asm volatile("s_waitcnt lgkmcnt(0)" ::: "memory");
            __builtin_amdgcn_sched_barrier(0);
            {   // bstep
                float ebl = eb * LOG2E, e1l = e1 * LOG2E;
                float e3l = e3 * LOG2E, e5l = e5 * LOG2E;
                float f0 = b0 + ebl;                 // beta[t+1][s'] + E[t+1][s']
                float f1 = b1 + e1l;
                float f2 = b2 + ebl;
                float f3 = b3 + e3l;
                float f0p = (lane == 63) ? NEGF : (q0 + ebl);   // == shfl(b0+eb)
                float f1p = (lane == 63) ? NEGF : (q1 + e5l);   // == shfl(b1+e1)
                float n0 = lse2(f0, f1);
                float n1 = lse3(f1, f2, skip3 ? f3 : NEGF);
                float n2 = lse2(f2, f3);
                float n3 = lse3(f3, f0p, skip5 ? f1p : NEGF);
                b0 = v0 ? n0 : NEGF;
                b1 = v1 ? n1 : NEGF;
                b2 = v2 ? n2 : NEGF;
                b3 = v3 ? n3 : NEGF;
                q0 = __shfl_down(b0, 1, 64);
                q1 = __shfl_down(b1, 1, 64);
            }
            asm volatile(VMW ::: "memory");
            uint32_t sb = ringb + (uint32_t)(((i + 1) & (RB - 1)) << 12);
            lds_read4(sb, o1, o3, o5, eb, e1, e3, e5);
        }
        asm volatile("s_waitcnt vmcnt(0) lgkmcnt(0)" ::: "memory");
        *((float4*)(wsB + (long)n * 256) + lane) = make_float4(b0, b1, b2, b3);
    }
}

// tot_n = logsumexp_s( alpha[tm][s] + beta[tm][s] );  out += -tot_n if finite
__global__ __launch_bounds__(64, 1)
void ctc_combine(const float* __restrict__ wsA, const float* __restrict__ wsB,
                 float* __restrict__ out)
{
    const int n = blockIdx.x;
    const int lane = threadIdx.x;
    const float4 A = *((const float4*)(wsA + (long)n * 256) + lane);
    const float4 B = *((const float4*)(wsB + (long)n * 256) + lane);
    float v = lse2(lse2(A.x + B.x, A.y + B.y), lse2(A.z + B.z, A.w + B.w));
    #pragma unroll
    for (int off = 1; off < 64; off <<= 1) {
        float o = __shfl_xor(v, off, 64);
        v = lse2(v, o);
    }
    if (lane == 0) {
        float tot = v * LN2F;                        // back to natural log
        if (tot > -1e29f) atomicAdd(out, -tot);
    }
}

extern "C" void kernel_launch(void* const* d_in, const int* in_sizes, int n_in,
                              void* d_out, int out_size, void* d_ws, size_t ws_size,
                              hipStream_t stream) {
    const float* lp      = (const float*)d_in[0];
    const int*   targets = (const int*)d_in[1];
    const int*   in_len  = (const int*)d_in[2];
    const int*   tgt_len = (const int*)d_in[3];
    const int N = in_sizes[2];
    const int L = in_sizes[1] / N;
    const int C = 1024;                              // fixed by the reference problem
    const int T = (int)((long)in_sizes[0] / ((long)N * C));

    float* out = (float*)d_out;
    float* wsA = (float*)d_ws;                       // N*256 floats
    float* wsB = wsA + (long)N * 256;                // N*256 floats  (total 64 KB)

    hipMemsetAsync(out, 0, sizeof(float), stream);
    ctc_scan<<<2 * N, 64, 0, stream>>>(lp, targets, in_len, tgt_len,
                                       wsA, wsB, T, N, C, L);
    ctc_combine<<<N, 64, 0, stream>>>(wsA, wsB, out);
}

// Round 2
// 336.618 us; speedup vs baseline: 1.2301x; 1.0485x over previous
//
#include <hip/hip_runtime.h>
#include <stdint.h>

#define NEGF  (-1e30f)
#define LOG2E 1.4426950408889634f
#define LN2F  0.6931471805599453f

__device__ __forceinline__ float fexp2(float x) {
#if __has_builtin(__builtin_amdgcn_exp2f)
    return __builtin_amdgcn_exp2f(x);
#else
    return exp2f(x);
#endif
}
__device__ __forceinline__ float flog2(float x) {
#if __has_builtin(__builtin_amdgcn_logf)
    return __builtin_amdgcn_logf(x);
#else
    return log2f(x);
#endif
}
__device__ __forceinline__ float lse2(float a, float b) {
    float m  = fmaxf(a, b);
    float mn = fminf(a, b);
    return m + flog2(1.0f + fexp2(mn - m));
}
__device__ __forceinline__ float lse3(float a, float b, float c) {
    float m = fmaxf(fmaxf(a, b), c);
    float s = fexp2(a - m) + fexp2(b - m) + fexp2(c - m);
    return m + flog2(s);
}

// Wave-wide lane shifts via gfx9 DPP (VALU, no lgkmcnt — unlike ds_bpermute).
// wave_shr:1 (0x138): lane i <- lane i-1  (== __shfl_up 1), lane 0 <- old
// wave_shl:1 (0x130): lane i <- lane i+1  (== __shfl_down 1), lane 63 <- old
__device__ __forceinline__ float dpp_shr1(float x, float fill) {
    int r = __builtin_amdgcn_update_dpp(__float_as_int(fill), __float_as_int(x),
                                        0x138, 0xf, 0xf, false);
    return __int_as_float(r);
}
__device__ __forceinline__ float dpp_shl1(float x, float fill) {
    int r = __builtin_amdgcn_update_dpp(__float_as_int(fill), __float_as_int(x),
                                        0x130, 0xf, 0xf, false);
    return __int_as_float(r);
}

// ---- LDS ring pipeline ------------------------------------------------------
// RB slots x 4KB (one full lp row, C=1024 f32) = 64 KB LDS.
// 4 global_load_lds (16B x 64 lanes = 1KB each) per row.
// vmcnt(52): 13 rows in flight allowed -> row consumed 2 steps ahead has landed.
#define RB  16
#define VMW "s_waitcnt vmcnt(52)"

__device__ __forceinline__ void stage_row(const float* __restrict__ src, float* dst)
{
    const int lane = threadIdx.x;
    const float* g = src + (lane << 2);              // lane*16B within row
    __builtin_amdgcn_global_load_lds((const __attribute__((address_space(1))) void*)(g),
        (__attribute__((address_space(3))) void*)(dst), 16, 0, 0);
    __builtin_amdgcn_global_load_lds((const __attribute__((address_space(1))) void*)(g + 256),
        (__attribute__((address_space(3))) void*)(dst + 256), 16, 0, 0);
    __builtin_amdgcn_global_load_lds((const __attribute__((address_space(1))) void*)(g + 512),
        (__attribute__((address_space(3))) void*)(dst + 512), 16, 0, 0);
    __builtin_amdgcn_global_load_lds((const __attribute__((address_space(1))) void*)(g + 768),
        (__attribute__((address_space(3))) void*)(dst + 768), 16, 0, 0);
}

// Inline-asm LDS gathers (opaque: compiler can never insert a draining wait).
// m0=-1 re-established because global_load_lds lowering clobbers m0.
__device__ __forceinline__ void lds_read3(uint32_t sb, uint32_t o1, uint32_t o3,
                                          float& eb, float& e1, float& e3)
{
    asm volatile("s_mov_b32 m0, -1\n\t"
                 "ds_read_b32 %0, %3\n\t"
                 "ds_read_b32 %1, %4\n\t"
                 "ds_read_b32 %2, %5"
                 : "=&v"(eb), "=&v"(e1), "=&v"(e3)
                 : "v"(sb), "v"(sb + o1), "v"(sb + o3)
                 : "memory");
}
__device__ __forceinline__ void lds_read4(uint32_t sb, uint32_t o1, uint32_t o3, uint32_t o5,
                                          float& eb, float& e1, float& e3, float& e5)
{
    asm volatile("s_mov_b32 m0, -1\n\t"
                 "ds_read_b32 %0, %4\n\t"
                 "ds_read_b32 %1, %5\n\t"
                 "ds_read_b32 %2, %6\n\t"
                 "ds_read_b32 %3, %7"
                 : "=&v"(eb), "=&v"(e1), "=&v"(e3), "=&v"(e5)
                 : "v"(sb), "v"(sb + o1), "v"(sb + o3), "v"(sb + o5)
                 : "memory");
}

// Counted lgkm waits TIED to the prefetched registers: consumers data-depend on
// the wait asm, so the compiler cannot hoist compute above it (m214 r263/r282).
#define LGKM_WAIT3(c, x0, x1, x2) \
    asm volatile("s_waitcnt lgkmcnt(" #c ")" : "+v"(x0), "+v"(x1), "+v"(x2) :: "memory")
#define LGKM_WAIT4(c, x0, x1, x2, x3) \
    asm volatile("s_waitcnt lgkmcnt(" #c ")" : "+v"(x0), "+v"(x1), "+v"(x2), "+v"(x3) :: "memory")

// One wave (64 lanes) per (utterance, direction). Lane i owns extended states
// 4i..4i+3 (S <= 201 <= 256). blockIdx.x <  N : forward alpha scan t=0..tm
//                             blockIdx.x >= N : backward beta  scan t=T-1..tm
__global__ __launch_bounds__(64, 1)
void ctc_scan(const float* __restrict__ lp, const int* __restrict__ tgt,
              const int* __restrict__ ilen, const int* __restrict__ tlen,
              float* __restrict__ wsA, float* __restrict__ wsB,
              int T, int N, int C, int L)
{
    __shared__ float ring[RB * 1024];                // 64 KB (C == 1024 fixed)

    const int  b      = blockIdx.x;
    const bool is_fwd = (b < N);
    const int  n      = is_fwd ? b : (b - N);
    const int  lane   = threadIdx.x;
    const int  len_t  = tlen[n];
    const int  len_in = ilen[n];
    const int  tm     = (len_in - 1) >> 1;
    const int  send   = 2 * len_t;                   // final blank state index

    const long tb = (long)n * L;
    auto getT = [&](int k) -> int {
        return (k >= 0 && k < len_t) ? tgt[tb + k] : 0;
    };
    const int lm1 = getT(2 * lane - 1);
    const int l1  = getT(2 * lane);                  // label of state 4i+1
    const int l2  = getT(2 * lane + 1);              // label of state 4i+3
    const int l3  = getT(2 * lane + 2);              // label of state 4i+5
    const uint32_t o1 = (uint32_t)l1 << 2;           // fixed per-lane LDS offsets
    const uint32_t o3 = (uint32_t)l2 << 2;
    const uint32_t o5 = (uint32_t)l3 << 2;
    const bool skip1 = (lane > 0) && (l1 != lm1);    // skip_ok[4i+1]
    const bool skip3 = (l2 != l1);                   // skip_ok[4i+3]
    const bool skip5 = (l3 != l2);                   // skip_ok[4i+5]
    const int  s0 = 4 * lane;

    const long   rstride = (long)N * C;              // floats per time row
    const float* row0    = lp + (long)n * C;
    const uint32_t ringb =
        (uint32_t)(uintptr_t)(const __attribute__((address_space(3))) void*)ring;

    // NOTE: per-step validity masking dropped — invalid states (> send) start at
    // NEGF and stay there exactly (f32: -1e30 + O(10) == -1e30); they contribute
    // exp2(-2e30 - m) == 0 in the combine. Init masking below is sufficient.

    if (is_fwd) {
        // ---- forward alpha: steps i=0..tm-1 consume rows 1..tm ----
        float eb0 = row0[0];
        float e10 = row0[l1];
        asm volatile("s_waitcnt vmcnt(0)" : "+v"(eb0), "+v"(e10) :: "memory");
        float a0 = (lane == 0) ? eb0 * LOG2E : NEGF;
        float a1 = (lane == 0 && 1 <= send) ? e10 * LOG2E : NEGF;
        float a2 = NEGF, a3 = NEGF;
        float p3 = NEGF;                             // shfl_up(a3) carried

        auto fstep = [&](float ebr, float e1r, float e3r) {
            float eb = ebr * LOG2E, e1 = e1r * LOG2E, e3 = e3r * LOG2E;
            float n0 = lse2(a0, p3) + eb;            // p3 == NEGF at lane 0 (DPP fill)
            float n1 = lse3(a1, a0, skip1 ? p3 : NEGF) + e1;
            float n2 = lse2(a2, a1) + eb;
            float n3 = lse3(a3, a2, skip3 ? a1 : NEGF) + e3;
            a0 = n0; a1 = n1; a2 = n2; a3 = n3;
            p3 = dpp_shr1(a3, NEGF);                 // for next step; VALU only
        };

        const int nsteps = tm;
        const int lim    = len_in - 1;
        for (int j = 0; j < RB - 1; ++j) {           // prologue: steps 0..14
            int r = 1 + j; if (r > lim) r = lim;
            stage_row(row0 + (long)r * rstride, ring + (j << 10));
        }
        asm volatile(VMW ::: "memory");              // rows for steps 0,1 landed
        float ebA, e1A, e3A, ebB, e1B, e3B;
        lds_read3(ringb,        o1, o3, ebA, e1A, e3A);   // step 0
        lds_read3(ringb + 4096, o1, o3, ebB, e1B, e3B);   // step 1

        int i = 0;
        for (; i + 1 < nsteps; i += 2) {
            {   int s = i + RB - 1; int r = s + 1; if (r > lim) r = lim;
                stage_row(row0 + (long)r * rstride, ring + ((s & (RB - 1)) << 10)); }
            LGKM_WAIT3(3, ebA, e1A, e3A);            // setB (3 reads) may stay in flight
            fstep(ebA, e1A, e3A);                    // step i
            asm volatile(VMW ::: "memory");          // row for step i+2 landed
            lds_read3(ringb + (uint32_t)(((i + 2) & (RB - 1)) << 12), o1, o3,
                      ebA, e1A, e3A);

            {   int s = i + RB; int r = s + 1; if (r > lim) r = lim;
                stage_row(row0 + (long)r * rstride, ring + ((s & (RB - 1)) << 10)); }
            LGKM_WAIT3(3, ebB, e1B, e3B);            // new setA stays in flight
            fstep(ebB, e1B, e3B);                    // step i+1
            asm volatile(VMW ::: "memory");          // row for step i+3 landed
            lds_read3(ringb + (uint32_t)(((i + 3) & (RB - 1)) << 12), o1, o3,
                      ebB, e1B, e3B);
        }
        if (i < nsteps) {                            // odd tail (nsteps=749)
            LGKM_WAIT3(0, ebA, e1A, e3A);
            fstep(ebA, e1A, e3A);
        }
        asm volatile("s_waitcnt vmcnt(0) lgkmcnt(0)" ::: "memory");
        *((float4*)(wsA + (long)n * 256) + lane) = make_float4(a0, a1, a2, a3);
    } else {
        // ---- backward beta: step k consumes row len_in-1-k, k=0..nsteps-1 ----
        float b0 = (s0     == send || s0     == send - 1) ? 0.0f : NEGF;
        float b1 = (s0 + 1 == send || s0 + 1 == send - 1) ? 0.0f : NEGF;
        float b2 = (s0 + 2 == send || s0 + 2 == send - 1) ? 0.0f : NEGF;
        float b3 = (s0 + 3 == send || s0 + 3 == send - 1) ? 0.0f : NEGF;
        float q0 = dpp_shl1(b0, NEGF);               // shfl_down(b0) carried
        float q1 = dpp_shl1(b1, NEGF);

        auto bstep = [&](float ebr, float e1r, float e3r, float e5r) {
            float ebl = ebr * LOG2E, e1l = e1r * LOG2E;
            float e3l = e3r * LOG2E, e5l = e5r * LOG2E;
            float f0 = b0 + ebl;                     // beta[t+1][s'] + E[t+1][s']
            float f1 = b1 + e1l;
            float f2 = b2 + ebl;
            float f3 = b3 + e3l;
            float f0p = q0 + ebl;                    // q0 == NEGF at lane 63
            float f1p = q1 + e5l;
            b0 = lse2(f0, f1);
            b1 = lse3(f1, f2, skip3 ? f3 : NEGF);
            b2 = lse2(f2, f3);
            b3 = lse3(f3, f0p, skip5 ? f1p : NEGF);
            q0 = dpp_shl1(b0, NEGF);
            q1 = dpp_shl1(b1, NEGF);
        };

        const int nsteps = len_in - 1 - tm;
        asm volatile("s_waitcnt vmcnt(0)" ::: "memory");   // drain preamble loads
        for (int j = 0; j < RB - 1; ++j) {           // prologue: steps 0..14
            int r = len_in - 1 - j; if (r < 0) r = 0;
            stage_row(row0 + (long)r * rstride, ring + (j << 10));
        }
        asm volatile(VMW ::: "memory");
        float ebA, e1A, e3A, e5A, ebB, e1B, e3B, e5B;
        lds_read4(ringb,        o1, o3, o5, ebA, e1A, e3A, e5A);  // step 0
        lds_read4(ringb + 4096, o1, o3, o5, ebB, e1B, e3B, e5B);  // step 1

        int i = 0;
        for (; i + 1 < nsteps; i += 2) {
            {   int s = i + RB - 1; int r = len_in - 1 - s; if (r < 0) r = 0;
                stage_row(row0 + (long)r * rstride, ring + ((s & (RB - 1)) << 10)); }
            LGKM_WAIT4(4, ebA, e1A, e3A, e5A);
            bstep(ebA, e1A, e3A, e5A);               // step i
            asm volatile(VMW ::: "memory");
            lds_read4(ringb + (uint32_t)(((i + 2) & (RB - 1)) << 12), o1, o3, o5,
                      ebA, e1A, e3A, e5A);

            {   int s = i + RB; int r = len_in - 1 - s; if (r < 0) r = 0;
                stage_row(row0 + (long)r * rstride, ring + ((s & (RB - 1)) << 10)); }
            LGKM_WAIT4(4, ebB, e1B, e3B, e5B);
            bstep(ebB, e1B, e3B, e5B);               // step i+1
            asm volatile(VMW ::: "memory");
            lds_read4(ringb + (uint32_t)(((i + 3) & (RB - 1)) << 12), o1, o3, o5,
                      ebB, e1B, e3B, e5B);
        }
        if (i < nsteps) {
            LGKM_WAIT4(0, ebA, e1A, e3A, e5A);
            bstep(ebA, e1A, e3A, e5A);
        }
        asm volatile("s_waitcnt vmcnt(0) lgkmcnt(0)" ::: "memory");
        *((float4*)(wsB + (long)n * 256) + lane) = make_float4(b0, b1, b2, b3);
    }
}

// tot_n = logsumexp_s( alpha[tm][s] + beta[tm][s] );  out += -tot_n if finite
__global__ __launch_bounds__(64, 1)
void ctc_combine(const float* __restrict__ wsA, const float* __restrict__ wsB,
                 float* __restrict__ out)
{
    const int n = blockIdx.x;
    const int lane = threadIdx.x;
    const float4 A = *((const float4*)(wsA + (long)n * 256) + lane);
    const float4 B = *((const float4*)(wsB + (long)n * 256) + lane);
    float v = lse2(lse2(A.x + B.x, A.y + B.y), lse2(A.z + B.z, A.w + B.w));
    #pragma unroll
    for (int off = 1; off < 64; off <<= 1) {
        float o = __shfl_xor(v, off, 64);
        v = lse2(v, o);
    }
    if (lane == 0) {
        float tot = v * LN2F;                        // back to natural log
        if (tot > -1e29f) atomicAdd(out, -tot);
    }
}

extern "C" void kernel_launch(void* const* d_in, const int* in_sizes, int n_in,
                              void* d_out, int out_size, void* d_ws, size_t ws_size,
                              hipStream_t stream) {
    const float* lp      = (const float*)d_in[0];
    const int*   targets = (const int*)d_in[1];
    const int*   in_len  = (const int*)d_in[2];
    const int*   tgt_len = (const int*)d_in[3];
    const int N = in_sizes[2];
    const int L = in_sizes[1] / N;
    const int C = 1024;                              // fixed by the reference problem
    const int T = (int)((long)in_sizes[0] / ((long)N * C));

    float* out = (float*)d_out;
    float* wsA = (float*)d_ws;                       // N*256 floats
    float* wsB = wsA + (long)N * 256;                // N*256 floats  (total 64 KB)

    hipMemsetAsync(out, 0, sizeof(float), stream);
    ctc_scan<<<2 * N, 64, 0, stream>>>(lp, targets, in_len, tgt_len,
                                       wsA, wsB, T, N, C, L);
    ctc_combine<<<N, 64, 0, stream>>>(wsA, wsB, out);
}

// Round 10
// 319.938 us; speedup vs baseline: 1.2943x; 1.0521x over previous
//
#include <hip/hip_runtime.h>
#include <stdint.h>

#define NEGF  (-1e30f)
#define LOG2E 1.4426950408889634f
#define LN2F  0.6931471805599453f

__device__ __forceinline__ float fexp2(float x) {
#if __has_builtin(__builtin_amdgcn_exp2f)
    return __builtin_amdgcn_exp2f(x);
#else
    return exp2f(x);
#endif
}
__device__ __forceinline__ float flog2(float x) {
#if __has_builtin(__builtin_amdgcn_logf)
    return __builtin_amdgcn_logf(x);
#else
    return log2f(x);
#endif
}
__device__ __forceinline__ float lse2(float a, float b) {
    float m  = fmaxf(a, b);
    float mn = fminf(a, b);
    return m + flog2(1.0f + fexp2(mn - m));
}

// DPP lane shifts (VALU-only; no lgkmcnt).
// wave_shr:1 = 0x138 (lane i <- i-1), wave_shl:1 = 0x130 (lane i <- i+1)
__device__ __forceinline__ float dpp_shr1(float x, float fill) {
    int r = __builtin_amdgcn_update_dpp(__float_as_int(fill), __float_as_int(x),
                                        0x138, 0xf, 0xf, false);
    return __int_as_float(r);
}
__device__ __forceinline__ float dpp_shl1(float x, float fill) {
    int r = __builtin_amdgcn_update_dpp(__float_as_int(fill), __float_as_int(x),
                                        0x130, 0xf, 0xf, false);
    return __int_as_float(r);
}

// ---- LDS ring pipeline ------------------------------------------------------
// 16 slots x 4KB (one lp row, C=1024 f32) = 64 KB LDS. 4 global_load_lds/row.
// vmcnt(44): <=11 rows in flight -> the row whose ds_read we issue next
// (step u+4, staged 11 slots earlier) has landed.
#define RB  16
#define VMW "s_waitcnt vmcnt(44)"

__device__ __forceinline__ void stage_row_c(const float* src, float* dst)
{
    const int lane = threadIdx.x;
    const float* g = src + (lane << 2);
    __builtin_amdgcn_global_load_lds((const __attribute__((address_space(1))) void*)(g),
        (__attribute__((address_space(3))) void*)(dst), 16, 0, 0);
    __builtin_amdgcn_global_load_lds((const __attribute__((address_space(1))) void*)(g + 256),
        (__attribute__((address_space(3))) void*)(dst + 256), 16, 0, 0);
    __builtin_amdgcn_global_load_lds((const __attribute__((address_space(1))) void*)(g + 512),
        (__attribute__((address_space(3))) void*)(dst + 512), 16, 0, 0);
    __builtin_amdgcn_global_load_lds((const __attribute__((address_space(1))) void*)(g + 768),
        (__attribute__((address_space(3))) void*)(dst + 768), 16, 0, 0);
}

// Opaque LDS gathers (compiler cannot insert a draining wait). m0=-1 restored
// (global_load_lds lowering clobbers m0 with the LDS base).
__device__ __forceinline__ void lds_read3(uint32_t sb, uint32_t o1, uint32_t o3,
                                          float& eb, float& e1, float& e3)
{
    asm volatile("s_mov_b32 m0, -1\n\t"
                 "ds_read_b32 %0, %3\n\t"
                 "ds_read_b32 %1, %4\n\t"
                 "ds_read_b32 %2, %5"
                 : "=&v"(eb), "=&v"(e1), "=&v"(e3)
                 : "v"(sb), "v"(sb + o1), "v"(sb + o3)
                 : "memory");
}
__device__ __forceinline__ void lds_read4(uint32_t sb, uint32_t o1, uint32_t o3, uint32_t o5,
                                          float& eb, float& e1, float& e3, float& e5)
{
    asm volatile("s_mov_b32 m0, -1\n\t"
                 "ds_read_b32 %0, %4\n\t"
                 "ds_read_b32 %1, %5\n\t"
                 "ds_read_b32 %2, %6\n\t"
                 "ds_read_b32 %3, %7"
                 : "=&v"(eb), "=&v"(e1), "=&v"(e3), "=&v"(e5)
                 : "v"(sb), "v"(sb + o1), "v"(sb + o3), "v"(sb + o5)
                 : "memory");
}

// Counted lgkm waits tied to the prefetched registers (anti-hoist, m214 r263).
#define LGKM_WAIT3(c, x0, x1, x2) \
    asm volatile("s_waitcnt lgkmcnt(" #c ")" : "+v"(x0), "+v"(x1), "+v"(x2) :: "memory")
#define LGKM_WAIT4(c, x0, x1, x2, x3) \
    asm volatile("s_waitcnt lgkmcnt(" #c ")" : "+v"(x0), "+v"(x1), "+v"(x2), "+v"(x3) :: "memory")

// ---- PER-LANE exponent renorm (every 8 steps) -------------------------------
// Each lane scales its 4 states to its OWN max (within-lane spread ~15 bits;
// cross-STATE range of alpha/beta is ~375 bits -> wave-wide renorm flushes the
// states the combine needs, r4 failure). esum (per-lane int) accumulates the
// scale; cross = 2^(esum_nbr - esum_self) converts the neighbor coupling term
// into self scale (constant between renorms). Exactly-zero lanes adopt the
// neighbor's esum so cross never blows up at the frontier. Subnormal-nonzero
// max: exact 2^126 rescale (NOT esum adoption - that would corrupt the scale).
// dpp_ctrl: fwd neighbor = lane-1 (0x138), bwd neighbor = lane+1 (0x130).
#define RENORM_LANE(x0, x1, x2, x3, DPPC)                                     \
  do {                                                                        \
    float m_ = fmaxf(fmaxf(x0, x1), fmaxf(x2, x3));                           \
    int   ei_ = (__float_as_int(m_) >> 23) & 0xff;                            \
    bool  z_  = (m_ == 0.0f);                                                 \
    float sc_ = z_ ? 1.0f : ((ei_ != 0) ? __int_as_float((254 - ei_) << 23)   \
                                        : __int_as_float(253 << 23));         \
    int   d_  = z_ ? 0 : ((ei_ != 0) ? (ei_ - 127) : -126);                   \
    int   eu_ = esum + d_;                                                    \
    int   en_ = __builtin_amdgcn_update_dpp(eu_, eu_, (DPPC), 0xf, 0xf, false);\
    esum = z_ ? en_ : eu_;                        /* zero lane adopts nbr */  \
    x0 *= sc_; x1 *= sc_; x2 *= sc_; x3 *= sc_;                               \
    int   ep_ = __builtin_amdgcn_update_dpp(esum, esum, (DPPC), 0xf, 0xf, false);\
    int   ce_ = ep_ - esum;                                                   \
    ce_ = ce_ < -126 ? -126 : (ce_ > 126 ? 126 : ce_);                        \
    cross = __int_as_float((ce_ + 127) << 23);                                \
  } while (0)

// One wave (64 lanes) per (utterance, direction). Lane i owns extended states
// 4i..4i+3 (S <= 201 <= 256). blockIdx.x <  N : forward alpha scan t=0..tm
//                             blockIdx.x >= N : backward beta  scan t=T-1..tm
// LINEAR-domain scan, blank-normalized each step, per-lane exponent tracking;
// ws output stays log2-domain.
__global__ __launch_bounds__(64, 1)
void ctc_scan(const float* __restrict__ lp, const int* __restrict__ tgt,
              const int* __restrict__ ilen, const int* __restrict__ tlen,
              float* __restrict__ wsA, float* __restrict__ wsB,
              int T, int N, int C, int L)
{
    __shared__ float ring[RB * 1024];                // 64 KB

    const int  b      = blockIdx.x;
    const bool is_fwd = (b < N);
    const int  n      = is_fwd ? b : (b - N);
    const int  lane   = threadIdx.x;
    const int  len_t  = tlen[n];
    const int  len_in = ilen[n];
    const int  tm     = (len_in - 1) >> 1;
    const int  send   = 2 * len_t;                   // final blank state index

    const long tb = (long)n * L;
    auto getT = [&](int k) -> int {
        return (k >= 0 && k < len_t) ? tgt[tb + k] : 0;
    };
    const int lm1 = getT(2 * lane - 1);
    const int l1  = getT(2 * lane);                  // label of state 4i+1
    const int l2  = getT(2 * lane + 1);              // label of state 4i+3
    const int l3  = getT(2 * lane + 2);              // label of state 4i+5
    const uint32_t o1 = (uint32_t)l1 << 2;
    const uint32_t o3 = (uint32_t)l2 << 2;
    const uint32_t o5 = (uint32_t)l3 << 2;
    const bool skip1 = (lane > 0) && (l1 != lm1);
    const bool skip3 = (l2 != l1);
    const bool skip5 = (l3 != l2);
    const int  s0 = 4 * lane;

    const long   rstride = (long)N * C;
    const float* row0    = lp + (long)n * C;
    const uint32_t ringb =
        (uint32_t)(uintptr_t)(const __attribute__((address_space(3))) void*)ring;

    int    esum  = 0;                                // per-lane power-of-2 scale
    float  cross = 1.0f;                             // 2^(esum_nbr - esum_self)
    double dsum  = 0.0;                              // wave-uniform blank log-sum

    if (is_fwd) {
        // ---- forward alpha (normalized): step i consumes row i+1 ----
        float eb0 = row0[0];
        float e10 = row0[l1];
        asm volatile("s_waitcnt vmcnt(0)" : "+v"(eb0), "+v"(e10) :: "memory");
        dsum = (double)eb0;          // true alpha = stored * 2^esum * exp(dsum)
        float a0 = (lane == 0) ? 1.0f : 0.0f;
        float a1 = (lane == 0 && 1 <= send) ? fexp2((e10 - eb0) * LOG2E) : 0.0f;
        float a2 = 0.0f, a3 = 0.0f;
        float p3 = 0.0f;                             // carried dpp_shr(a3)*cross

        const int nsteps = tm;
        const int lim    = len_in - 1;
        for (int j = 0; j < RB - 1; ++j) {           // prologue: rows for steps 0..14
            int r = 1 + j; if (r > lim) r = lim;
            stage_row_c(row0 + (long)r * rstride, ring + (j << 10));
        }
        int rr = (16 > lim) ? lim : 16;              // next row to stage
        const float* pstage = row0 + (long)rr * rstride;

        asm volatile(VMW ::: "memory");              // rows for steps 0..3 landed
        float rb0, r1_0, r3_0, rb1, r1_1, r3_1;
        float rb2, r1_2, r3_2, rb3, r1_3, r3_3;
        lds_read3(ringb,         o1, o3, rb0, r1_0, r3_0);   // step 0
        lds_read3(ringb + 4096,  o1, o3, rb1, r1_1, r3_1);   // step 1
        lds_read3(ringb + 8192,  o1, o3, rb2, r1_2, r3_2);   // step 2
        lds_read3(ringb + 12288, o1, o3, rb3, r1_3, r3_3);   // step 3

// 4 register sets, slot pattern u&3: realigns every 16 slots -> NO end-of-block
// register rotation (rotation would copy regs with in-flight ds_read writes).
#define FSLOT(u, s)                                                            \
  do {                                                                         \
    stage_row_c(pstage, ring + ((((u) + 15) & 15) << 10));                     \
    { int adv = (rr < lim); rr += adv; pstage += adv ? rstride : 0; }          \
    asm volatile(VMW ::: "memory");                                            \
    LGKM_WAIT3(9, rb##s, r1_##s, r3_##s);                                      \
    float cb = rb##s, c1v = r1_##s, c3v = r3_##s;                              \
    lds_read3(ringb + ((((u) + 4) & 15) << 12), o1, o3, rb##s, r1_##s, r3_##s);\
    float rv1 = fexp2((c1v - cb) * LOG2E);                                     \
    float rv3 = fexp2((c3v - cb) * LOG2E);                                     \
    dsum += (double)cb;                                                        \
    float n0 = a0 + p3;                                                        \
    float n1 = (a1 + a0 + (skip1 ? p3 : 0.0f)) * rv1;                          \
    float n2 = a2 + a1;                                                        \
    float n3 = (a3 + a2 + (skip3 ? a1 : 0.0f)) * rv3;                          \
    a0 = n0; a1 = n1; a2 = n2; a3 = n3;                                        \
    p3 = dpp_shr1(a3, 0.0f) * cross;                                           \
  } while (0)

#define RENORM_F() do { RENORM_LANE(a0, a1, a2, a3, 0x138);                    \
                        p3 = dpp_shr1(a3, 0.0f) * cross; } while (0)

        int i = 0;
        while (i + 16 <= nsteps) {
            FSLOT(0,0);  FSLOT(1,1);  FSLOT(2,2);  FSLOT(3,3);
            FSLOT(4,0);  FSLOT(5,1);  FSLOT(6,2);  FSLOT(7,3);
            RENORM_F();
            FSLOT(8,0);  FSLOT(9,1);  FSLOT(10,2); FSLOT(11,3);
            FSLOT(12,0); FSLOT(13,1); FSLOT(14,2); FSLOT(15,3);
            RENORM_F();
            i += 16;
        }
        // Liveness-extending drain: keeps all set registers alive until every
        // in-flight ds_read/vmem retires, so the allocator cannot recycle a
        // register that hardware will still write (use-after-free race).
        asm volatile("s_waitcnt vmcnt(0) lgkmcnt(0)"
                     :: "v"(rb0), "v"(r1_0), "v"(r3_0), "v"(rb1), "v"(r1_1), "v"(r3_1),
                        "v"(rb2), "v"(r1_2), "v"(r3_2), "v"(rb3), "v"(r1_3), "v"(r3_3)
                     : "memory");
        for (; i < nsteps; ++i) {                    // tail (< 16 steps)
            float cb, c1v, c3v;
            lds_read3(ringb + (uint32_t)((i & 15) << 12), o1, o3, cb, c1v, c3v);
            LGKM_WAIT3(0, cb, c1v, c3v);
            float rv1 = fexp2((c1v - cb) * LOG2E);
            float rv3 = fexp2((c3v - cb) * LOG2E);
            dsum += (double)cb;
            float n0 = a0 + p3;
            float n1 = (a1 + a0 + (skip1 ? p3 : 0.0f)) * rv1;
            float n2 = a2 + a1;
            float n3 = (a3 + a2 + (skip3 ? a1 : 0.0f)) * rv3;
            a0 = n0; a1 = n1; a2 = n2; a3 = n3;
            p3 = dpp_shr1(a3, 0.0f) * cross;
            if ((i & 7) == 7) RENORM_F();
        }
        float S  = (float)(dsum * 1.4426950408889634);
        float fe = (float)esum;
        float w0 = fmaxf(flog2(a0) + fe + S, NEGF);
        float w1 = fmaxf(flog2(a1) + fe + S, NEGF);
        float w2 = fmaxf(flog2(a2) + fe + S, NEGF);
        float w3 = fmaxf(flog2(a3) + fe + S, NEGF);
        *((float4*)(wsA + (long)n * 256) + lane) = make_float4(w0, w1, w2, w3);
#undef FSLOT
#undef RENORM_F
    } else {
        // ---- backward beta (normalized): step k consumes row len_in-1-k ----
        float b0 = (s0     == send || s0     == send - 1) ? 1.0f : 0.0f;
        float b1 = (s0 + 1 == send || s0 + 1 == send - 1) ? 1.0f : 0.0f;
        float b2 = (s0 + 2 == send || s0 + 2 == send - 1) ? 1.0f : 0.0f;
        float b3 = (s0 + 3 == send || s0 + 3 == send - 1) ? 1.0f : 0.0f;
        float q0 = dpp_shl1(b0, 0.0f);               // carried lane+1 b0 * cross
        float q1 = dpp_shl1(b1, 0.0f);               // carried lane+1 b1 * cross

        const int nsteps = len_in - 1 - tm;
        for (int j = 0; j < RB - 1; ++j) {           // prologue: rows for steps 0..14
            int r = len_in - 1 - j; if (r < 0) r = 0;
            stage_row_c(row0 + (long)r * rstride, ring + (j << 10));
        }
        int rr = len_in - 16; if (rr < 0) rr = 0;    // next row to stage
        const float* pstage = row0 + (long)rr * rstride;

        asm volatile(VMW ::: "memory");              // rows for steps 0..3 landed
        float rb0, r1_0, r3_0, r5_0, rb1, r1_1, r3_1, r5_1;
        float rb2, r1_2, r3_2, r5_2, rb3, r1_3, r3_3, r5_3;
        lds_read4(ringb,         o1, o3, o5, rb0, r1_0, r3_0, r5_0);  // step 0
        lds_read4(ringb + 4096,  o1, o3, o5, rb1, r1_1, r3_1, r5_1);  // step 1
        lds_read4(ringb + 8192,  o1, o3, o5, rb2, r1_2, r3_2, r5_2);  // step 2
        lds_read4(ringb + 12288, o1, o3, o5, rb3, r1_3, r3_3, r5_3);  // step 3

#define BSLOT(u, s)                                                            \
  do {                                                                         \
    stage_row_c(pstage, ring + ((((u) + 15) & 15) << 10));                     \
    { int adv = (rr > 0); rr -= adv; pstage -= adv ? rstride : 0; }            \
    asm volatile(VMW ::: "memory");                                            \
    LGKM_WAIT4(12, rb##s, r1_##s, r3_##s, r5_##s);                             \
    float cb = rb##s, c1v = r1_##s, c3v = r3_##s, c5v = r5_##s;                \
    lds_read4(ringb + ((((u) + 4) & 15) << 12), o1, o3, o5,                    \
              rb##s, r1_##s, r3_##s, r5_##s);                                  \
    float rv1 = fexp2((c1v - cb) * LOG2E);                                     \
    float rv3 = fexp2((c3v - cb) * LOG2E);                                     \
    float rv5 = fexp2((c5v - cb) * LOG2E);                                     \
    dsum += (double)cb;                                                        \
    float g1 = b1 * rv1, g3 = b3 * rv3;                                        \
    float n0 = b0 + g1;                                                        \
    float n1 = g1 + b2 + (skip3 ? g3 : 0.0f);                                  \
    float n2 = b2 + g3;                                                        \
    float n3 = g3 + q0 + (skip5 ? q1 * rv5 : 0.0f);                            \
    b0 = n0; b1 = n1; b2 = n2; b3 = n3;                                        \
    q0 = dpp_shl1(b0, 0.0f) * cross;                                           \
    q1 = dpp_shl1(b1, 0.0f) * cross;                                           \
  } while (0)

#define RENORM_B() do { RENORM_LANE(b0, b1, b2, b3, 0x130);                    \
                        q0 = dpp_shl1(b0, 0.0f) * cross;                       \
                        q1 = dpp_shl1(b1, 0.0f) * cross; } while (0)

        int i = 0;
        while (i + 16 <= nsteps) {
            BSLOT(0,0);  BSLOT(1,1);  BSLOT(2,2);  BSLOT(3,3);
            BSLOT(4,0);  BSLOT(5,1);  BSLOT(6,2);  BSLOT(7,3);
            RENORM_B();
            BSLOT(8,0);  BSLOT(9,1);  BSLOT(10,2); BSLOT(11,3);
            BSLOT(12,0); BSLOT(13,1); BSLOT(14,2); BSLOT(15,3);
            RENORM_B();
            i += 16;
        }
        asm volatile("s_waitcnt vmcnt(0) lgkmcnt(0)"
                     :: "v"(rb0), "v"(r1_0), "v"(r3_0), "v"(r5_0),
                        "v"(rb1), "v"(r1_1), "v"(r3_1), "v"(r5_1),
                        "v"(rb2), "v"(r1_2), "v"(r3_2), "v"(r5_2),
                        "v"(rb3), "v"(r1_3), "v"(r3_3), "v"(r5_3)
                     : "memory");
        for (; i < nsteps; ++i) {                    // tail (< 16 steps)
            float cb, c1v, c3v, c5v;
            lds_read4(ringb + (uint32_t)((i & 15) << 12), o1, o3, o5,
                      cb, c1v, c3v, c5v);
            LGKM_WAIT4(0, cb, c1v, c3v, c5v);
            float rv1 = fexp2((c1v - cb) * LOG2E);
            float rv3 = fexp2((c3v - cb) * LOG2E);
            float rv5 = fexp2((c5v - cb) * LOG2E);
            dsum += (double)cb;
            float g1 = b1 * rv1, g3 = b3 * rv3;
            float n0 = b0 + g1;
            float n1 = g1 + b2 + (skip3 ? g3 : 0.0f);
            float n2 = b2 + g3;
            float n3 = g3 + q0 + (skip5 ? q1 * rv5 : 0.0f);
            b0 = n0; b1 = n1; b2 = n2; b3 = n3;
            q0 = dpp_shl1(b0, 0.0f) * cross;
            q1 = dpp_shl1(b1, 0.0f) * cross;
            if ((i & 7) == 7) RENORM_B();
        }
        float S  = (float)(dsum * 1.4426950408889634);
        float fe = (float)esum;
        float w0 = fmaxf(flog2(b0) + fe + S, NEGF);
        float w1 = fmaxf(flog2(b1) + fe + S, NEGF);
        float w2 = fmaxf(flog2(b2) + fe + S, NEGF);
        float w3 = fmaxf(flog2(b3) + fe + S, NEGF);
        *((float4*)(wsB + (long)n * 256) + lane) = make_float4(w0, w1, w2, w3);
#undef BSLOT
#undef RENORM_B
    }
}

// tot_n = logsumexp_s( alpha[tm][s] + beta[tm][s] );  out += -tot_n if finite
__global__ __launch_bounds__(64, 1)
void ctc_combine(const float* __restrict__ wsA, const float* __restrict__ wsB,
                 float* __restrict__ out)
{
    const int n = blockIdx.x;
    const int lane = threadIdx.x;
    const float4 A = *((const float4*)(wsA + (long)n * 256) + lane);
    const float4 B = *((const float4*)(wsB + (long)n * 256) + lane);
    float v = lse2(lse2(A.x + B.x, A.y + B.y), lse2(A.z + B.z, A.w + B.w));
    #pragma unroll
    for (int off = 1; off < 64; off <<= 1) {
        float o = __shfl_xor(v, off, 64);
        v = lse2(v, o);
    }
    if (lane == 0) {
        float tot = v * LN2F;                        // back to natural log
        if (tot > -1e29f) atomicAdd(out, -tot);
    }
}

extern "C" void kernel_launch(void* const* d_in, const int* in_sizes, int n_in,
                              void* d_out, int out_size, void* d_ws, size_t ws_size,
                              hipStream_t stream) {
    const float* lp      = (const float*)d_in[0];
    const int*   targets = (const int*)d_in[1];
    const int*   in_len  = (const int*)d_in[2];
    const int*   tgt_len = (const int*)d_in[3];
    const int N = in_sizes[2];
    const int L = in_sizes[1] / N;
    const int C = 1024;                              // fixed by the reference problem
    const int T = (int)((long)in_sizes[0] / ((long)N * C));

    float* out = (float*)d_out;
    float* wsA = (float*)d_ws;                       // N*256 floats
    float* wsB = wsA + (long)N * 256;                // N*256 floats

    hipMemsetAsync(out, 0, sizeof(float), stream);
    ctc_scan<<<2 * N, 64, 0, stream>>>(lp, targets, in_len, tgt_len,
                                       wsA, wsB, T, N, C, L);
    ctc_combine<<<N, 64, 0, stream>>>(wsA, wsB, out);
}

// Round 11
// 312.166 us; speedup vs baseline: 1.3265x; 1.0249x over previous
//
#include <hip/hip_runtime.h>
#include <stdint.h>

#define NEGF  (-1e30f)
#define LOG2E 1.4426950408889634f
#define LN2F  0.6931471805599453f

__device__ __forceinline__ float fexp2(float x) {
#if __has_builtin(__builtin_amdgcn_exp2f)
    return __builtin_amdgcn_exp2f(x);
#else
    return exp2f(x);
#endif
}
__device__ __forceinline__ float flog2(float x) {
#if __has_builtin(__builtin_amdgcn_logf)
    return __builtin_amdgcn_logf(x);
#else
    return log2f(x);
#endif
}
__device__ __forceinline__ float lse2(float a, float b) {
    float m  = fmaxf(a, b);
    float mn = fminf(a, b);
    return m + flog2(1.0f + fexp2(mn - m));
}

// DPP lane shifts (VALU-only; no lgkmcnt).
// wave_shr:1 = 0x138 (lane i <- i-1), wave_shl:1 = 0x130 (lane i <- i+1)
__device__ __forceinline__ float dpp_shr1(float x, float fill) {
    int r = __builtin_amdgcn_update_dpp(__float_as_int(fill), __float_as_int(x),
                                        0x138, 0xf, 0xf, false);
    return __int_as_float(r);
}
__device__ __forceinline__ float dpp_shl1(float x, float fill) {
    int r = __builtin_amdgcn_update_dpp(__float_as_int(fill), __float_as_int(x),
                                        0x130, 0xf, 0xf, false);
    return __int_as_float(r);
}

// ---- 4-wave cooperative LDS ring ------------------------------------------
// 32 slots x 4KB row = 128KB LDS, organized as 8 groups of 4 steps.
// Each of the 4 waves stages one 1KB quarter of each row (1 global_load_lds
// width=16 per wave per row) -> 4x the per-wave outstanding-VMEM budget that
// capped every previous version at ~10 B/cyc/CU.
// Per loop iter (1 group = 4 steps): stage group g+6 (4 instr/wave), then
// per-wave vmcnt(20) (groups g+1..g+5 stay in flight; g+1 drains), then ONE
// raw s_barrier (per-wave vmcnt BEFORE barrier => no pipeline drain), then
// wave 0 consumes group g. Overwrite safety: stage(g+6) hits ring-group g-2,
// which all waves passed barrier_{g-1} after wave0 consumed it.
#define VMW "s_waitcnt vmcnt(20)"

// Opaque LDS gathers (compiler cannot insert a draining wait). m0=-1 restored
// (global_load_lds lowering clobbers m0 with the LDS base).
__device__ __forceinline__ void lds_read3(uint32_t sb, uint32_t o1, uint32_t o3,
                                          float& eb, float& e1, float& e3)
{
    asm volatile("s_mov_b32 m0, -1\n\t"
                 "ds_read_b32 %0, %3\n\t"
                 "ds_read_b32 %1, %4\n\t"
                 "ds_read_b32 %2, %5"
                 : "=&v"(eb), "=&v"(e1), "=&v"(e3)
                 : "v"(sb), "v"(sb + o1), "v"(sb + o3)
                 : "memory");
}
__device__ __forceinline__ void lds_read4(uint32_t sb, uint32_t o1, uint32_t o3, uint32_t o5,
                                          float& eb, float& e1, float& e3, float& e5)
{
    asm volatile("s_mov_b32 m0, -1\n\t"
                 "ds_read_b32 %0, %4\n\t"
                 "ds_read_b32 %1, %5\n\t"
                 "ds_read_b32 %2, %6\n\t"
                 "ds_read_b32 %3, %7"
                 : "=&v"(eb), "=&v"(e1), "=&v"(e3), "=&v"(e5)
                 : "v"(sb), "v"(sb + o1), "v"(sb + o3), "v"(sb + o5)
                 : "memory");
}

// Counted lgkm waits tied to the prefetched registers (anti-hoist, m214 r263).
#define LGKM_WAIT3(c, x0, x1, x2) \
    asm volatile("s_waitcnt lgkmcnt(" #c ")" : "+v"(x0), "+v"(x1), "+v"(x2) :: "memory")
#define LGKM_WAIT4(c, x0, x1, x2, x3) \
    asm volatile("s_waitcnt lgkmcnt(" #c ")" : "+v"(x0), "+v"(x1), "+v"(x2), "+v"(x3) :: "memory")

// ---- PER-LANE exponent renorm (every 8 steps) — HW-validated in r10 --------
#define RENORM_LANE(x0, x1, x2, x3, DPPC)                                     \
  do {                                                                        \
    float m_ = fmaxf(fmaxf(x0, x1), fmaxf(x2, x3));                           \
    int   ei_ = (__float_as_int(m_) >> 23) & 0xff;                            \
    bool  z_  = (m_ == 0.0f);                                                 \
    float sc_ = z_ ? 1.0f : ((ei_ != 0) ? __int_as_float((254 - ei_) << 23)   \
                                        : __int_as_float(253 << 23));         \
    int   d_  = z_ ? 0 : ((ei_ != 0) ? (ei_ - 127) : -126);                   \
    int   eu_ = esum + d_;                                                    \
    int   en_ = __builtin_amdgcn_update_dpp(eu_, eu_, (DPPC), 0xf, 0xf, false);\
    esum = z_ ? en_ : eu_;                        /* zero lane adopts nbr */  \
    x0 *= sc_; x1 *= sc_; x2 *= sc_; x3 *= sc_;                               \
    int   ep_ = __builtin_amdgcn_update_dpp(esum, esum, (DPPC), 0xf, 0xf, false);\
    int   ce_ = ep_ - esum;                                                   \
    ce_ = ce_ < -126 ? -126 : (ce_ > 126 ? 126 : ce_);                        \
    cross = __int_as_float((ce_ + 127) << 23);                                \
  } while (0)

// One 256-thread block (4 waves) per (utterance, direction).
// Wave 0: serial scan (lane i owns ext states 4i..4i+3, S <= 201 <= 256).
// All 4 waves: cooperative row staging. blockIdx.x < N: fwd; else bwd.
// LINEAR-domain scan, blank-normalized, per-lane exponent tracking (r10).
__global__ __launch_bounds__(256, 1)
void ctc_scan(const float* __restrict__ lp, const int* __restrict__ tgt,
              const int* __restrict__ ilen, const int* __restrict__ tlen,
              float* __restrict__ wsA, float* __restrict__ wsB,
              int T, int N, int C, int L)
{
    __shared__ float ring[32 * 1024];                // 128 KB (C == 1024 fixed)

    const int  b      = blockIdx.x;
    const bool is_fwd = (b < N);
    const int  n      = is_fwd ? b : (b - N);
    const int  lane   = threadIdx.x & 63;
    const int  wid    = threadIdx.x >> 6;
    const int  len_t  = tlen[n];
    const int  len_in = ilen[n];
    const int  tm     = (len_in - 1) >> 1;
    const int  send   = 2 * len_t;                   // final blank state index
    const int  lim    = len_in - 1;

    const long tb = (long)n * L;
    auto getT = [&](int k) -> int {
        return (k >= 0 && k < len_t) ? tgt[tb + k] : 0;
    };
    const int lm1 = getT(2 * lane - 1);
    const int l1  = getT(2 * lane);                  // label of state 4i+1
    const int l2  = getT(2 * lane + 1);              // label of state 4i+3
    const int l3  = getT(2 * lane + 2);              // label of state 4i+5
    const uint32_t o1 = (uint32_t)l1 << 2;
    const uint32_t o3 = (uint32_t)l2 << 2;
    const uint32_t o5 = (uint32_t)l3 << 2;
    const bool skip1 = (lane > 0) && (l1 != lm1);
    const bool skip3 = (l2 != l1);
    const bool skip5 = (l3 != l2);
    const int  s0 = 4 * lane;

    const long   rstride = (long)N * C;
    const float* row0    = lp + (long)n * C;
    const int    qbase   = wid << 8;                 // this wave's quarter (floats)
    const uint32_t ringb =
        (uint32_t)(uintptr_t)(const __attribute__((address_space(3))) void*)ring;

    const int nsteps  = is_fwd ? tm : (len_in - 1 - tm);
    const int ngroups = nsteps >> 2;

    // stage the 4 rows of step-group G (this wave's quarter of each)
    auto stage_group = [&](int G) {
        #pragma unroll
        for (int j = 0; j < 4; ++j) {
            int s = 4 * G + j;
            long r = is_fwd ? (long)(1 + s) : (long)(len_in - 1 - s);
            if (r > lim) r = lim;
            if (r < 0)  r = 0;
            const float* src = row0 + r * rstride + qbase + (lane << 2);
            float*       dst = ring + ((s & 31) << 10) + qbase;
            __builtin_amdgcn_global_load_lds(
                (const __attribute__((address_space(1))) void*)src,
                (__attribute__((address_space(3))) void*)dst, 16, 0, 0);
        }
    };

    int    esum  = 0;                                // per-lane power-of-2 scale
    float  cross = 1.0f;                             // 2^(esum_nbr - esum_self)
    double dsum  = 0.0;                              // wave-uniform blank log-sum

    // ---- preamble state init (all waves compute; only wave 0 uses it) ----
    float a0, a1, a2, a3, p3;                        // fwd alpha  (or unused)
    float b0, b1, b2, b3, q0, q1;                    // bwd beta   (or unused)
    if (is_fwd) {
        float eb0 = row0[0];
        float e10 = row0[l1];
        asm volatile("s_waitcnt vmcnt(0)" : "+v"(eb0), "+v"(e10) :: "memory");
        dsum = (double)eb0;          // true alpha = stored * 2^esum * exp(dsum)
        a0 = (lane == 0) ? 1.0f : 0.0f;
        a1 = (lane == 0 && 1 <= send) ? fexp2((e10 - eb0) * LOG2E) : 0.0f;
        a2 = 0.0f; a3 = 0.0f; p3 = 0.0f;
    } else {
        asm volatile("s_waitcnt vmcnt(0)" ::: "memory");   // drain tgt gathers
        b0 = (s0     == send || s0     == send - 1) ? 1.0f : 0.0f;
        b1 = (s0 + 1 == send || s0 + 1 == send - 1) ? 1.0f : 0.0f;
        b2 = (s0 + 2 == send || s0 + 2 == send - 1) ? 1.0f : 0.0f;
        b3 = (s0 + 3 == send || s0 + 3 == send - 1) ? 1.0f : 0.0f;
        q0 = dpp_shl1(b0, 0.0f);
        q1 = dpp_shl1(b1, 0.0f);
    }

    // ---- prologue: stage groups 0..5 (24 instr/wave), land group 0 ----
    for (int G = 0; G < 6; ++G) stage_group(G);
    asm volatile(VMW ::: "memory");                  // drains group 0

    // ================= main loop: 1 barrier per 4 steps =================
    for (int g = 0; g < ngroups; ++g) {
        stage_group(g + 6);                          // overwrites group g-2
        asm volatile(VMW ::: "memory");              // drains group g+1
        __builtin_amdgcn_s_barrier();                // group g ready for wave 0
        if (wid == 0) {
            uint32_t sb = ringb + (uint32_t)(((4 * g) & 31) << 12);
            if (is_fwd) {
                float cb0,c10,c30, cb1,c11,c31, cb2,c12,c32, cb3,c13,c33;
                lds_read3(sb,         o1, o3, cb0, c10, c30);
                lds_read3(sb + 4096,  o1, o3, cb1, c11, c31);
                lds_read3(sb + 8192,  o1, o3, cb2, c12, c32);
                lds_read3(sb + 12288, o1, o3, cb3, c13, c33);
#define FSTEP(cb, c1v, c3v)                                                   \
  do {                                                                        \
    float rv1 = fexp2(((c1v) - (cb)) * LOG2E);                                \
    float rv3 = fexp2(((c3v) - (cb)) * LOG2E);                                \
    float n0 = a0 + p3;                                                       \
    float n1 = (a1 + a0 + (skip1 ? p3 : 0.0f)) * rv1;                         \
    float n2 = a2 + a1;                                                       \
    float n3 = (a3 + a2 + (skip3 ? a1 : 0.0f)) * rv3;                         \
    a0 = n0; a1 = n1; a2 = n2; a3 = n3;                                       \
    p3 = dpp_shr1(a3, 0.0f) * cross;                                          \
  } while (0)
                LGKM_WAIT3(9, cb0, c10, c30); FSTEP(cb0, c10, c30);
                LGKM_WAIT3(6, cb1, c11, c31); FSTEP(cb1, c11, c31);
                LGKM_WAIT3(3, cb2, c12, c32); FSTEP(cb2, c12, c32);
                LGKM_WAIT3(0, cb3, c13, c33); FSTEP(cb3, c13, c33);
                dsum += (double)((cb0 + cb1) + (cb2 + cb3));
                if (g & 1) {                         // every 8 steps
                    RENORM_LANE(a0, a1, a2, a3, 0x138);
                    p3 = dpp_shr1(a3, 0.0f) * cross;
                }
            } else {
                float cb0,c10,c30,c50, cb1,c11,c31,c51;
                float cb2,c12,c32,c52, cb3,c13,c33,c53;
                lds_read4(sb,         o1, o3, o5, cb0, c10, c30, c50);
                lds_read4(sb + 4096,  o1, o3, o5, cb1, c11, c31, c51);
                lds_read4(sb + 8192,  o1, o3, o5, cb2, c12, c32, c52);
                lds_read4(sb + 12288, o1, o3, o5, cb3, c13, c33, c53);
#define BSTEP(cb, c1v, c3v, c5v)                                              \
  do {                                                                        \
    float rv1 = fexp2(((c1v) - (cb)) * LOG2E);                                \
    float rv3 = fexp2(((c3v) - (cb)) * LOG2E);                                \
    float rv5 = fexp2(((c5v) - (cb)) * LOG2E);                                \
    float g1 = b1 * rv1, g3 = b3 * rv3;                                       \
    float n0 = b0 + g1;                                                       \
    float n1 = g1 + b2 + (skip3 ? g3 : 0.0f);                                 \
    float n2 = b2 + g3;                                                       \
    float n3 = g3 + q0 + (skip5 ? q1 * rv5 : 0.0f);                           \
    b0 = n0; b1 = n1; b2 = n2; b3 = n3;                                       \
    q0 = dpp_shl1(b0, 0.0f) * cross;                                          \
    q1 = dpp_shl1(b1, 0.0f) * cross;                                          \
  } while (0)
                LGKM_WAIT4(12, cb0, c10, c30, c50); BSTEP(cb0, c10, c30, c50);
                LGKM_WAIT4(8,  cb1, c11, c31, c51); BSTEP(cb1, c11, c31, c51);
                LGKM_WAIT4(4,  cb2, c12, c32, c52); BSTEP(cb2, c12, c32, c52);
                LGKM_WAIT4(0,  cb3, c13, c33, c53); BSTEP(cb3, c13, c33, c53);
                dsum += (double)((cb0 + cb1) + (cb2 + cb3));
                if (g & 1) {
                    RENORM_LANE(b0, b1, b2, b3, 0x130);
                    q0 = dpp_shl1(b0, 0.0f) * cross;
                    q1 = dpp_shl1(b1, 0.0f) * cross;
                }
            }
        }
    }

    // ---- tail: drain everything, then wave 0 finishes < 4 steps ----
    asm volatile("s_waitcnt vmcnt(0) lgkmcnt(0)" ::: "memory");
    __builtin_amdgcn_s_barrier();
    if (wid == 0) {
        if (is_fwd) {
            for (int i = 4 * ngroups; i < nsteps; ++i) {
                float cb, c1v, c3v;
                lds_read3(ringb + (uint32_t)((i & 31) << 12), o1, o3, cb, c1v, c3v);
                LGKM_WAIT3(0, cb, c1v, c3v);
                FSTEP(cb, c1v, c3v);
                dsum += (double)cb;
            }
            float S  = (float)(dsum * 1.4426950408889634);
            float fe = (float)esum;
            float w0 = fmaxf(flog2(a0) + fe + S, NEGF);
            float w1 = fmaxf(flog2(a1) + fe + S, NEGF);
            float w2 = fmaxf(flog2(a2) + fe + S, NEGF);
            float w3 = fmaxf(flog2(a3) + fe + S, NEGF);
            *((float4*)(wsA + (long)n * 256) + lane) = make_float4(w0, w1, w2, w3);
        } else {
            for (int i = 4 * ngroups; i < nsteps; ++i) {
                float cb, c1v, c3v, c5v;
                lds_read4(ringb + (uint32_t)((i & 31) << 12), o1, o3, o5,
                          cb, c1v, c3v, c5v);
                LGKM_WAIT4(0, cb, c1v, c3v, c5v);
                BSTEP(cb, c1v, c3v, c5v);
                dsum += (double)cb;
            }
            float S  = (float)(dsum * 1.4426950408889634);
            float fe = (float)esum;
            float w0 = fmaxf(flog2(b0) + fe + S, NEGF);
            float w1 = fmaxf(flog2(b1) + fe + S, NEGF);
            float w2 = fmaxf(flog2(b2) + fe + S, NEGF);
            float w3 = fmaxf(flog2(b3) + fe + S, NEGF);
            *((float4*)(wsB + (long)n * 256) + lane) = make_float4(w0, w1, w2, w3);
        }
    }
#undef FSTEP
#undef BSTEP
}

// tot_n = logsumexp_s( alpha[tm][s] + beta[tm][s] );  out += -tot_n if finite
__global__ __launch_bounds__(64, 1)
void ctc_combine(const float* __restrict__ wsA, const float* __restrict__ wsB,
                 float* __restrict__ out)
{
    const int n = blockIdx.x;
    const int lane = threadIdx.x;
    const float4 A = *((const float4*)(wsA + (long)n * 256) + lane);
    const float4 B = *((const float4*)(wsB + (long)n * 256) + lane);
    float v = lse2(lse2(A.x + B.x, A.y + B.y), lse2(A.z + B.z, A.w + B.w));
    #pragma unroll
    for (int off = 1; off < 64; off <<= 1) {
        float o = __shfl_xor(v, off, 64);
        v = lse2(v, o);
    }
    if (lane == 0) {
        float tot = v * LN2F;                        // back to natural log
        if (tot > -1e29f) atomicAdd(out, -tot);
    }
}

extern "C" void kernel_launch(void* const* d_in, const int* in_sizes, int n_in,
                              void* d_out, int out_size, void* d_ws, size_t ws_size,
                              hipStream_t stream) {
    const float* lp      = (const float*)d_in[0];
    const int*   targets = (const int*)d_in[1];
    const int*   in_len  = (const int*)d_in[2];
    const int*   tgt_len = (const int*)d_in[3];
    const int N = in_sizes[2];
    const int L = in_sizes[1] / N;
    const int C = 1024;                              // fixed by the reference problem
    const int T = (int)((long)in_sizes[0] / ((long)N * C));

    float* out = (float*)d_out;
    float* wsA = (float*)d_ws;                       // N*256 floats
    float* wsB = wsA + (long)N * 256;                // N*256 floats

    hipMemsetAsync(out, 0, sizeof(float), stream);
    ctc_scan<<<2 * N, 256, 0, stream>>>(lp, targets, in_len, tgt_len,
                                        wsA, wsB, T, N, C, L);
    ctc_combine<<<N, 64, 0, stream>>>(wsA, wsB, out);
}